// Round 8
// baseline (620.472 us; speedup 1.0000x reference)
//
#include <hip/hip_runtime.h>
#include <hip/hip_fp16.h>

// CapsuleLayer dynamic routing — round 12: fused 3-round kernel + LICM blocker.
// Round-11 post-mortem: fusing the rd loop into the kernel let LICM prove the
// hat2 computation (Wc loads + fdot2 chains, __restrict__, rd-invariant) was
// loop-invariant and hoist it out of the round loop — reconstructing the
// 120-reg resident-hat design and re-spilling it (WRITE_SIZE 290MB, the same
// scratch signature as rounds 6-9; dur 309us = 600MB scratch @ 2.2TB/s).
// Recompute-per-round only exists if the compiler can't prove it redundant.
// Fix: per-round opaque pointer barrier — asm volatile("" : "+v"(ptr)) on
// Wc/X/bias at the top of each rd iteration. Volatile identity asm can't be
// CSE'd or hoisted, so loads through the pointer are re-issued each round and
// hat2 stays a 40-reg slice-scoped temporary (proven spill-free in round 10:
// VGPR=68). W re-streams from per-XCD L2 (~66us for 3 rounds) instead of
// scratch HBM (~273us). Everything else identical to round 11.

#define IC 1152
#define IE 8
#define NC 10
#define DV 16
#define NB 256
#define NW (IC * NC * IE * DV)  // 1,474,560
#define SOUT (NC * DV)          // 160
#define NWAVE 12
#define TPB (NWAVE * 64)        // 768
#define NGPW 3                  // Gp groups per wave (36 = 12*3)

typedef _Float16 h2 __attribute__((ext_vector_type(2)));
union WChunk { int4 v; h2 p[4]; _Float16 h[8]; };
union XFrag { int4 v; h2 p[4]; };

#if defined(__has_builtin) && __has_builtin(__builtin_amdgcn_fdot2)
__device__ inline float fdot2(h2 a, h2 b, float c) {
    return __builtin_amdgcn_fdot2(a, b, c, false);
}
#else
__device__ inline float fdot2(h2 a, h2 b, float c) {
    return fmaf((float)a.x, (float)b.x, fmaf((float)a.y, (float)b.y, c));
}
#endif

// W fp32 [i][j][e][d] -> fp16 chunks Wc[((Gp*10+j)*8+k)*64 + lane], where
// lane = h*32+r, i = Gp*32+r, d = h*8+k; chunk holds e=0..7 halves of W[i,j,:,d].
__global__ void wprep_kernel(const float* __restrict__ W, int4* __restrict__ Wc) {
    const int t = blockIdx.x * blockDim.x + threadIdx.x;
    if (t >= NW / 8) return;
    const int lane = t & 63;
    const int h = lane >> 5, r = lane & 31;
    const int k = (t >> 6) & 7;
    const int r2 = t >> 9;  // Gp*10 + j
    const int j = r2 % NC, Gp = r2 / NC;
    const int i = Gp * 32 + r;
    const int d = h * 8 + k;
    const float* src = W + ((size_t)(i * NC + j) * IE) * DV + d;  // e-stride DV
    WChunk c;
#pragma unroll
    for (int e = 0; e < IE; ++e) c.h[e] = (_Float16)src[(size_t)e * DV];
    Wc[t] = c.v;
}

// Fused 3-round routing. Block = one batch element b; wave w owns Gp in
// {3w..3w+2}; lane g = h*32+r covers row i=Gp*32+r, d-half h = d/8.
// Per (round, Gp-slice): recompute hat for all 10 j (40 h2 regs, slice-scoped),
// thread-local softmax over j (logits use the running v-sum identity:
// b_r = b0 + <hat, sum_{r'<r} v_{r'}>), butterfly-reduce s into the wave's
// exclusive LDS slab; per round: reduce slabs + squash + update vc/v2s.
__global__ __launch_bounds__(TPB) void caps_kernel(
    const float* __restrict__ X,     // [B, IC, IE] fp32
    const int4* __restrict__ Wc,     // coalesced fp16 W (see wprep)
    const float* __restrict__ bias,  // [IC*NC] fp32
    float* __restrict__ out)         // [B, NC, DV]
{
    __shared__ float s_part[NWAVE * SOUT];      // per-wave exclusive slabs (7.5KB)
    __shared__ float vc[SOUT];                  // running v1+v2 (f32)
    __shared__ __align__(16) h2 v2s[SOUT / 2];  // running v packed for fdot2

    const int b = blockIdx.x;
    const int tid = threadIdx.x;
    const int w = tid >> 6;  // wave 0..11
    const int g = tid & 63;
    const int h = g >> 5;    // d-half: d = h*8 + k
    const int r = g & 31;    // row within 32-row group

    // zero own slab (wave-private; each wave accumulates only into its own)
    for (int idx = g; idx < SOUT; idx += 64) s_part[w * SOUT + idx] = 0.f;

    for (int rd = 0; rd < 3; ++rd) {
        // LICM blocker: opaque per-round copies of the input pointers. Loads
        // through these cannot be proven rd-invariant, so hat2 is recomputed
        // per round (40-reg slice temp) instead of hoisted (120-reg spill).
        const int4* wcr = Wc;
        const float* xr_ = X;
        const float* br_ = bias;
        asm volatile("" : "+v"(wcr), "+v"(xr_), "+v"(br_));

#pragma unroll
        for (int gl = 0; gl < NGPW; ++gl) {
            const int Gp = NGPW * w + gl;
            const int i = Gp * 32 + r;

            // ---- X row (L1/L2-resident after round 0), packed to h2 ----
            XFrag xu;
            {
                const float4* xr = (const float4*)(xr_ + ((size_t)b * IC + i) * IE);
                const float4 x0 = xr[0], x1 = xr[1];
                xu.p[0] = h2{(_Float16)x0.x, (_Float16)x0.y};
                xu.p[1] = h2{(_Float16)x0.z, (_Float16)x0.w};
                xu.p[2] = h2{(_Float16)x1.x, (_Float16)x1.y};
                xu.p[3] = h2{(_Float16)x1.z, (_Float16)x1.w};
            }

            // ---- hat for all 10 j of this slice (40 h2 regs, slice-scoped) ----
            h2 hat2[NC][4];
#pragma unroll
            for (int j = 0; j < NC; ++j) {
                const int4* wp = wcr + ((size_t)(Gp * NC + j)) * 512 + g;
                WChunk wk[4];
                float hat[8];
#pragma unroll
                for (int k = 0; k < 4; ++k) wk[k].v = wp[k * 64];
#pragma unroll
                for (int k = 0; k < 4; ++k) {
                    float a = 0.f;
#pragma unroll
                    for (int q = 0; q < 4; ++q) a = fdot2(xu.p[q], wk[k].p[q], a);
                    hat[k] = a;
                }
#pragma unroll
                for (int k = 0; k < 4; ++k) wk[k].v = wp[(k + 4) * 64];
#pragma unroll
                for (int k = 0; k < 4; ++k) {
                    float a = 0.f;
#pragma unroll
                    for (int q = 0; q < 4; ++q) a = fdot2(xu.p[q], wk[k].p[q], a);
                    hat[k + 4] = a;
                }
#pragma unroll
                for (int q = 0; q < 4; ++q)
                    hat2[j][q] = h2{(_Float16)hat[2 * q], (_Float16)hat[2 * q + 1]};
            }

            // ---- logits + THREAD-LOCAL softmax over j ----
            float c[NC];
            {
                float Z = 0.f;
#pragma unroll
                for (int j = 0; j < NC; ++j) {
                    float lt = br_[i * NC + j];
                    if (rd > 0) {
                        XFrag vv;
                        vv.v = *(const int4*)(v2s + (j * 8 + h * 4));
                        float ah = 0.f;
#pragma unroll
                        for (int q = 0; q < 4; ++q) ah = fdot2(hat2[j][q], vv.p[q], ah);
                        lt += ah + __shfl_xor(ah, 32);  // combine d-halves
                    }
                    const float e = __expf(lt);
                    c[j] = e;
                    Z += e;
                }
                const float rz = 1.f / Z;
#pragma unroll
                for (int j = 0; j < NC; ++j) c[j] *= rz;
            }

            // ---- weighted sum: butterfly over 32 r-lanes per j, += wave slab ----
#pragma unroll
            for (int j = 0; j < NC; ++j) {
                float s8[8];
#pragma unroll
                for (int q = 0; q < 4; ++q) {
                    s8[2 * q]     = c[j] * (float)hat2[j][q].x;
                    s8[2 * q + 1] = c[j] * (float)hat2[j][q].y;
                }
                float t4[4];
#pragma unroll
                for (int d = 0; d < 4; ++d) {
                    const bool hi = (r & 16);
                    const float mine = hi ? s8[d + 4] : s8[d];
                    const float send = hi ? s8[d] : s8[d + 4];
                    t4[d] = mine + __shfl_xor(send, 16);
                }
                float t2[2];
#pragma unroll
                for (int d = 0; d < 2; ++d) {
                    const bool hi = (r & 8);
                    const float mine = hi ? t4[d + 2] : t4[d];
                    const float send = hi ? t4[d] : t4[d + 2];
                    t2[d] = mine + __shfl_xor(send, 8);
                }
                float t1;
                {
                    const bool hi = (r & 4);
                    const float mine = hi ? t2[1] : t2[0];
                    const float send = hi ? t2[0] : t2[1];
                    t1 = mine + __shfl_xor(send, 4);
                }
                t1 += __shfl_xor(t1, 2);
                t1 += __shfl_xor(t1, 1);
                if ((r & 3) == 0) {
                    const int dl = (r >> 2) & 7;  // bit map: r4->d2, r3->d1, r2->d0
                    s_part[w * SOUT + j * DV + h * 8 + dl] += t1;
                }
            }
        }
        __syncthreads();  // slabs complete

        // ---- reduce slabs + squash; update running v (or write output) ----
        if (tid < SOUT) {
            float sv = 0.f;
#pragma unroll
            for (int ww = 0; ww < NWAVE; ++ww) sv += s_part[ww * SOUT + tid];
            float s2 = sv * sv;
#pragma unroll
            for (int mk = 8; mk >= 1; mk >>= 1) s2 += __shfl_xor(s2, mk, 16);
            const float scale = sqrtf(s2) / (1.f + s2);
            const float vv = scale * sv;
            if (rd == 2) {
                out[(size_t)b * SOUT + tid] = vv;
            } else {
                const float vcum = (rd == 0) ? vv : (vc[tid] + vv);
                vc[tid] = vcum;
                const float oth = __shfl_xor(vcum, 1);
                if (!(tid & 1)) v2s[tid >> 1] = h2{(_Float16)vcum, (_Float16)oth};
            }
        }
        __syncthreads();  // v2s visible; slab reads done

        if (rd < 2) {  // re-zero own slab for the next round
            for (int idx = g; idx < SOUT; idx += 64) s_part[w * SOUT + idx] = 0.f;
        }
    }
}

extern "C" void kernel_launch(void* const* d_in, const int* in_sizes, int n_in,
                              void* d_out, int out_size, void* d_ws, size_t ws_size,
                              hipStream_t stream) {
    const float* X = (const float*)d_in[0];     // [256,1152,8]
    const float* W = (const float*)d_in[1];     // [1152,10,8,16]
    const float* bias = (const float*)d_in[2];  // [1,1152,10]
    float* out = (float*)d_out;

    int4* Wc = (int4*)d_ws;  // ws: Wc only (2.95 MB)

    wprep_kernel<<<dim3(720), dim3(256), 0, stream>>>(W, Wc);
    caps_kernel<<<dim3(NB), dim3(TPB), 0, stream>>>(X, Wc, bias, out);
}

// Round 9
// 316.317 us; speedup vs baseline: 1.9616x; 1.9616x over previous
//
#include <hip/hip_runtime.h>
#include <hip/hip_fp16.h>

// CapsuleLayer dynamic routing — round 13: 3-launch recompute (no hat storage).
// Round-8/12 post-mortem: fusing the round loop in-kernel loses either way —
// LICM hoists the rd-invariant hat computation into a 120-reg live range and
// spills it (r11: 290MB scratch), and opaque-pointer asm barriers block the
// hoist but force VGPR-pair flat addressing that spills the slice temporaries
// instead (r12: 1.15GB scratch, 620us). Kernel-launch boundaries are the one
// LICM barrier the compiler cannot cross. Round 10 proved this per-launch body
// spill-free (VGPR=68, WRITE~out only); its hat-STORE path measured 147.7us
// with ~135us being 283MB of HBM hat traffic. This round measures the
// RECOMPUTE path: 3 round launches, each re-streaming W from the per-XCD L2
// (2.95MB/block ~ 22us/round) — predicted 75-95us total.
// Per kernel: block = one b; wave w owns Gp in {3w..3w+2}; thread-local
// softmax over j (no logit LDS, no barriers in the hot loop); hat held only
// as a 40-h2 slice temp; per-wave exclusive s slabs; squash fused.

#define IC 1152
#define IE 8
#define NC 10
#define DV 16
#define NB 256
#define NW (IC * NC * IE * DV)  // 1,474,560
#define SOUT (NC * DV)          // 160
#define NWAVE 12
#define TPB (NWAVE * 64)        // 768
#define NGPW 3                  // Gp groups per wave (36 = 12*3)

typedef _Float16 h2 __attribute__((ext_vector_type(2)));
union WChunk { int4 v; h2 p[4]; _Float16 h[8]; };
union XFrag { int4 v; h2 p[4]; };

#if defined(__has_builtin) && __has_builtin(__builtin_amdgcn_fdot2)
__device__ inline float fdot2(h2 a, h2 b, float c) {
    return __builtin_amdgcn_fdot2(a, b, c, false);
}
#else
__device__ inline float fdot2(h2 a, h2 b, float c) {
    return fmaf((float)a.x, (float)b.x, fmaf((float)a.y, (float)b.y, c));
}
#endif

// W fp32 [i][j][e][d] -> fp16 chunks Wc[((Gp*10+j)*8+k)*64 + lane], where
// lane = h*32+r, i = Gp*32+r, d = h*8+k; chunk holds e=0..7 halves of W[i,j,:,d].
__global__ void wprep_kernel(const float* __restrict__ W, int4* __restrict__ Wc) {
    const int t = blockIdx.x * blockDim.x + threadIdx.x;
    if (t >= NW / 8) return;
    const int lane = t & 63;
    const int h = lane >> 5, r = lane & 31;
    const int k = (t >> 6) & 7;
    const int r2 = t >> 9;  // Gp*10 + j
    const int j = r2 % NC, Gp = r2 / NC;
    const int i = Gp * 32 + r;
    const int d = h * 8 + k;
    const float* src = W + ((size_t)(i * NC + j) * IE) * DV + d;  // e-stride DV
    WChunk c;
#pragma unroll
    for (int e = 0; e < IE; ++e) c.h[e] = (_Float16)src[(size_t)e * DV];
    Wc[t] = c.v;
}

// One routing round (host-side rd loop = the LICM barrier).
// RD=0: c = softmax(bias); writes v1.
// RD=1: logits use v1; writes vsum = v1 + squash(s).
// RD=2: logits use vsum; writes final output.
template <int RD>
__global__ __launch_bounds__(TPB) void round_caps(
    const float* __restrict__ X,     // [B, IC, IE] fp32
    const int4* __restrict__ Wc,     // coalesced fp16 W (see wprep)
    const float* __restrict__ bias,  // [IC*NC] fp32
    const float* __restrict__ v_in,  // [B*160] or unused (RD=0)
    float* __restrict__ v_out)       // [B*160] (v1 / vsum / final out)
{
    __shared__ float s_part[NWAVE * SOUT];      // per-wave exclusive slabs (7.5KB)
    __shared__ __align__(16) h2 v2s[SOUT / 2];  // v_in packed for fdot2

    const int b = blockIdx.x;
    const int tid = threadIdx.x;
    const int w = tid >> 6;  // wave 0..11
    const int g = tid & 63;
    const int h = g >> 5;    // d-half: d = h*8 + k
    const int r = g & 31;    // row within 32-row group

    float vkeep = 0.f;  // v1 value carried into the vsum write (RD==1)
    if constexpr (RD > 0) {
        if (RD == 1 && tid < SOUT) vkeep = v_in[(size_t)b * SOUT + tid];
        if (tid < SOUT / 2) {
            const float* vp = v_in + (size_t)b * SOUT + 2 * tid;
            v2s[tid] = h2{(_Float16)vp[0], (_Float16)vp[1]};
        }
    }
    // zero own slab (wave-private: no barrier needed before accumulation)
    for (int idx = g; idx < SOUT; idx += 64) s_part[w * SOUT + idx] = 0.f;
    if constexpr (RD > 0) __syncthreads();  // v2s ready

#pragma unroll
    for (int gl = 0; gl < NGPW; ++gl) {
        const int Gp = NGPW * w + gl;
        const int i = Gp * 32 + r;

        // ---- X row packed to h2 (L1/L2-hit after round 0) ----
        XFrag xu;
        {
            const float4* xr = (const float4*)(X + ((size_t)b * IC + i) * IE);
            const float4 x0 = xr[0], x1 = xr[1];
            xu.p[0] = h2{(_Float16)x0.x, (_Float16)x0.y};
            xu.p[1] = h2{(_Float16)x0.z, (_Float16)x0.w};
            xu.p[2] = h2{(_Float16)x1.x, (_Float16)x1.y};
            xu.p[3] = h2{(_Float16)x1.z, (_Float16)x1.w};
        }

        // ---- hat for all 10 j of this slice (40 h2 regs, slice-scoped) ----
        h2 hat2[NC][4];
#pragma unroll
        for (int j = 0; j < NC; ++j) {
            const int4* wp = Wc + ((size_t)(Gp * NC + j)) * 512 + g;
            WChunk wk[4];
            float hat[8];
#pragma unroll
            for (int k = 0; k < 4; ++k) wk[k].v = wp[k * 64];
#pragma unroll
            for (int k = 0; k < 4; ++k) {
                float a = 0.f;
#pragma unroll
                for (int q = 0; q < 4; ++q) a = fdot2(xu.p[q], wk[k].p[q], a);
                hat[k] = a;
            }
#pragma unroll
            for (int k = 0; k < 4; ++k) wk[k].v = wp[(k + 4) * 64];
#pragma unroll
            for (int k = 0; k < 4; ++k) {
                float a = 0.f;
#pragma unroll
                for (int q = 0; q < 4; ++q) a = fdot2(xu.p[q], wk[k].p[q], a);
                hat[k + 4] = a;
            }
#pragma unroll
            for (int q = 0; q < 4; ++q)
                hat2[j][q] = h2{(_Float16)hat[2 * q], (_Float16)hat[2 * q + 1]};
        }

        // ---- logits + THREAD-LOCAL softmax over j ----
        float c[NC];
        {
            float Z = 0.f;
#pragma unroll
            for (int j = 0; j < NC; ++j) {
                float lt = bias[i * NC + j];
                if constexpr (RD > 0) {
                    XFrag vv;
                    vv.v = *(const int4*)(v2s + (j * 8 + h * 4));
                    float ah = 0.f;
#pragma unroll
                    for (int q = 0; q < 4; ++q) ah = fdot2(hat2[j][q], vv.p[q], ah);
                    lt += ah + __shfl_xor(ah, 32);  // combine d-halves
                }
                const float e = __expf(lt);
                c[j] = e;
                Z += e;
            }
            const float rz = 1.f / Z;
#pragma unroll
            for (int j = 0; j < NC; ++j) c[j] *= rz;
        }

        // ---- weighted sum: butterfly over 32 r-lanes per j, += wave slab ----
#pragma unroll
        for (int j = 0; j < NC; ++j) {
            float s8[8];
#pragma unroll
            for (int q = 0; q < 4; ++q) {
                s8[2 * q]     = c[j] * (float)hat2[j][q].x;
                s8[2 * q + 1] = c[j] * (float)hat2[j][q].y;
            }
            float t4[4];
#pragma unroll
            for (int d = 0; d < 4; ++d) {
                const bool hi = (r & 16);
                const float mine = hi ? s8[d + 4] : s8[d];
                const float send = hi ? s8[d] : s8[d + 4];
                t4[d] = mine + __shfl_xor(send, 16);
            }
            float t2[2];
#pragma unroll
            for (int d = 0; d < 2; ++d) {
                const bool hi = (r & 8);
                const float mine = hi ? t4[d + 2] : t4[d];
                const float send = hi ? t4[d] : t4[d + 2];
                t2[d] = mine + __shfl_xor(send, 8);
            }
            float t1;
            {
                const bool hi = (r & 4);
                const float mine = hi ? t2[1] : t2[0];
                const float send = hi ? t2[0] : t2[1];
                t1 = mine + __shfl_xor(send, 4);
            }
            t1 += __shfl_xor(t1, 2);
            t1 += __shfl_xor(t1, 1);
            if ((r & 3) == 0) {
                const int dl = (r >> 2) & 7;  // bit map: r4->d2, r3->d1, r2->d0
                s_part[w * SOUT + j * DV + h * 8 + dl] += t1;
            }
        }
    }
    __syncthreads();

    // ---- reduce slabs + squash (+ v1 add for vsum) ----
    if (tid < SOUT) {
        float sv = 0.f;
#pragma unroll
        for (int ww = 0; ww < NWAVE; ++ww) sv += s_part[ww * SOUT + tid];
        float s2 = sv * sv;
#pragma unroll
        for (int mk = 8; mk >= 1; mk >>= 1) s2 += __shfl_xor(s2, mk, 16);
        const float scale = sqrtf(s2) / (1.f + s2);
        float vv = scale * sv;
        if constexpr (RD == 1) vv += vkeep;  // vsum = v1 + v2
        v_out[(size_t)b * SOUT + tid] = vv;
    }
}

extern "C" void kernel_launch(void* const* d_in, const int* in_sizes, int n_in,
                              void* d_out, int out_size, void* d_ws, size_t ws_size,
                              hipStream_t stream) {
    const float* X = (const float*)d_in[0];     // [256,1152,8]
    const float* W = (const float*)d_in[1];     // [1152,10,8,16]
    const float* bias = (const float*)d_in[2];  // [1,1152,10]
    float* out = (float*)d_out;

    // ws layout: Wc (2.95MB) | v1 (160KB) | vsum (160KB)
    int4* Wc = (int4*)d_ws;
    float* v1 = (float*)(Wc + NW / 8);
    float* vsum = v1 + (size_t)NB * SOUT;

    wprep_kernel<<<dim3(720), dim3(256), 0, stream>>>(W, Wc);

    dim3 grid(NB);
    round_caps<0><<<grid, TPB, 0, stream>>>(X, Wc, bias, nullptr, v1);
    round_caps<1><<<grid, TPB, 0, stream>>>(X, Wc, bias, v1, vsum);
    round_caps<2><<<grid, TPB, 0, stream>>>(X, Wc, bias, vsum, out);
}

// Round 10
// 176.614 us; speedup vs baseline: 3.5132x; 1.7910x over previous
//
#include <hip/hip_runtime.h>
#include <hip/hip_fp16.h>

// CapsuleLayer dynamic routing — round 14: register-shaved 3-launch recompute.
// Round-13 post-mortem: separate launches DID stop LICM, but the recompute
// body itself peaked at ~90-95 VGPRs (hat2 40 + c 10 + wk 16 + f32 hat 8 +
// misc) against the toolchain's immovable 84 budget -> wholesale spill of the
// unrolled arrays (353MB scratch/dispatch, ~160us each, scratch-BW-bound).
// Fix = design under 84 with margin:
//  * RD0: c=softmax(bias) is hat-independent -> compute c first, hat is a
//    4-h2 transient per j, butterfly immediately. Peak ~35 regs.
//  * RD1/2: W loaded as 2-int4 pairs (8-reg transient, was 16), hat packed to
//    h2 pairwise (2 f32 live, was 8), logit <hat_j,v> fused into the hat loop
//    (no second v2s pass); 1/Z folded into c_j in pass B. Peak ~70 regs.
// Skeleton unchanged (proven): block = one b, 12 waves x 3 Gp-groups,
// thread-local softmax over j, per-wave exclusive s slabs, fused squash,
// host-side rd loop as the LICM barrier.

#define IC 1152
#define IE 8
#define NC 10
#define DV 16
#define NB 256
#define NW (IC * NC * IE * DV)  // 1,474,560
#define SOUT (NC * DV)          // 160
#define NWAVE 12
#define TPB (NWAVE * 64)        // 768
#define NGPW 3                  // Gp groups per wave (36 = 12*3)

typedef _Float16 h2 __attribute__((ext_vector_type(2)));
union WChunk { int4 v; h2 p[4]; _Float16 h[8]; };
union XFrag { int4 v; h2 p[4]; };

#if defined(__has_builtin) && __has_builtin(__builtin_amdgcn_fdot2)
__device__ inline float fdot2(h2 a, h2 b, float c) {
    return __builtin_amdgcn_fdot2(a, b, c, false);
}
#else
__device__ inline float fdot2(h2 a, h2 b, float c) {
    return fmaf((float)a.x, (float)b.x, fmaf((float)a.y, (float)b.y, c));
}
#endif

// W fp32 [i][j][e][d] -> fp16 chunks Wc[((Gp*10+j)*8+k)*64 + lane], where
// lane = h*32+r, i = Gp*32+r, d = h*8+k; chunk holds e=0..7 halves of W[i,j,:,d].
__global__ void wprep_kernel(const float* __restrict__ W, int4* __restrict__ Wc) {
    const int t = blockIdx.x * blockDim.x + threadIdx.x;
    if (t >= NW / 8) return;
    const int lane = t & 63;
    const int h = lane >> 5, r = lane & 31;
    const int k = (t >> 6) & 7;
    const int r2 = t >> 9;  // Gp*10 + j
    const int j = r2 % NC, Gp = r2 / NC;
    const int i = Gp * 32 + r;
    const int d = h * 8 + k;
    const float* src = W + ((size_t)(i * NC + j) * IE) * DV + d;  // e-stride DV
    WChunk c;
#pragma unroll
    for (int e = 0; e < IE; ++e) c.h[e] = (_Float16)src[(size_t)e * DV];
    Wc[t] = c.v;
}

// Splitting butterfly over the 32 r-lanes of one d-half: s8[8] -> one value
// per (r&~3 group), accumulated into slab8[dl] (slab8 = &s_part[w][j*DV+h*8]).
__device__ inline void butterfly_acc(const float* s8, int r, float* slab8) {
    float t4[4];
#pragma unroll
    for (int d = 0; d < 4; ++d) {
        const bool hi = (r & 16);
        const float mine = hi ? s8[d + 4] : s8[d];
        const float send = hi ? s8[d] : s8[d + 4];
        t4[d] = mine + __shfl_xor(send, 16);
    }
    float t2[2];
#pragma unroll
    for (int d = 0; d < 2; ++d) {
        const bool hi = (r & 8);
        const float mine = hi ? t4[d + 2] : t4[d];
        const float send = hi ? t4[d] : t4[d + 2];
        t2[d] = mine + __shfl_xor(send, 8);
    }
    float t1;
    {
        const bool hi = (r & 4);
        const float mine = hi ? t2[1] : t2[0];
        const float send = hi ? t2[0] : t2[1];
        t1 = mine + __shfl_xor(send, 4);
    }
    t1 += __shfl_xor(t1, 2);
    t1 += __shfl_xor(t1, 1);
    if ((r & 3) == 0) {
        const int dl = (r >> 2) & 7;  // bit map: r4->d2, r3->d1, r2->d0
        slab8[dl] += t1;
    }
}

// One routing round (host-side rd loop = the LICM barrier).
// RD=0: c = softmax(bias); writes v1.
// RD=1: logits use v1; writes vsum = v1 + squash(s).
// RD=2: logits use vsum; writes final output.
template <int RD>
__global__ __launch_bounds__(TPB) void round_caps(
    const float* __restrict__ X,     // [B, IC, IE] fp32
    const int4* __restrict__ Wc,     // coalesced fp16 W (see wprep)
    const float* __restrict__ bias,  // [IC*NC] fp32
    const float* __restrict__ v_in,  // [B*160] or unused (RD=0)
    float* __restrict__ v_out)       // [B*160] (v1 / vsum / final out)
{
    __shared__ float s_part[NWAVE * SOUT];      // per-wave exclusive slabs (7.5KB)
    __shared__ __align__(16) h2 v2s[SOUT / 2];  // v_in packed for fdot2

    const int b = blockIdx.x;
    const int tid = threadIdx.x;
    const int w = tid >> 6;  // wave 0..11
    const int g = tid & 63;
    const int h = g >> 5;    // d-half: d = h*8 + k
    const int r = g & 31;    // row within 32-row group

    float vkeep = 0.f;  // v1 value carried into the vsum write (RD==1)
    if constexpr (RD > 0) {
        if (RD == 1 && tid < SOUT) vkeep = v_in[(size_t)b * SOUT + tid];
        if (tid < SOUT / 2) {
            const float* vp = v_in + (size_t)b * SOUT + 2 * tid;
            v2s[tid] = h2{(_Float16)vp[0], (_Float16)vp[1]};
        }
    }
    // zero own slab (wave-private: no barrier needed before accumulation)
    for (int idx = g; idx < SOUT; idx += 64) s_part[w * SOUT + idx] = 0.f;
    if constexpr (RD > 0) __syncthreads();  // v2s ready

#pragma unroll
    for (int gl = 0; gl < NGPW; ++gl) {
        const int Gp = NGPW * w + gl;
        const int i = Gp * 32 + r;

        // ---- X row packed to h2 (L1/L2-hit after first read) ----
        XFrag xu;
        {
            const float4* xr = (const float4*)(X + ((size_t)b * IC + i) * IE);
            const float4 x0 = xr[0], x1 = xr[1];
            xu.p[0] = h2{(_Float16)x0.x, (_Float16)x0.y};
            xu.p[1] = h2{(_Float16)x0.z, (_Float16)x0.w};
            xu.p[2] = h2{(_Float16)x1.x, (_Float16)x1.y};
            xu.p[3] = h2{(_Float16)x1.z, (_Float16)x1.w};
        }
        const int4* wpg = Wc + (size_t)(Gp * NC) * 512 + g;
        float* slab = &s_part[w * SOUT + h * 8];  // + j*DV per j

        if constexpr (RD == 0) {
            // ---- c = softmax(bias) first (hat-independent), then per-j
            // transient hat + immediate butterfly. Peak ~35 regs. ----
            float cj[NC];
            float Z = 0.f;
#pragma unroll
            for (int j = 0; j < NC; ++j) {
                const float e = __expf(bias[i * NC + j]);
                cj[j] = e;
                Z += e;
            }
            const float rz = 1.f / Z;
#pragma unroll
            for (int j = 0; j < NC; ++j) cj[j] *= rz;

#pragma unroll
            for (int j = 0; j < NC; ++j) {
                const int4* wp = wpg + j * 512;
                float s8[8];
#pragma unroll
                for (int kp = 0; kp < 4; ++kp) {
                    WChunk w0, w1;
                    w0.v = wp[(2 * kp) * 64];
                    w1.v = wp[(2 * kp + 1) * 64];
                    float a0 = 0.f, a1 = 0.f;
#pragma unroll
                    for (int q = 0; q < 4; ++q) {
                        a0 = fdot2(xu.p[q], w0.p[q], a0);
                        a1 = fdot2(xu.p[q], w1.p[q], a1);
                    }
                    s8[2 * kp] = cj[j] * a0;
                    s8[2 * kp + 1] = cj[j] * a1;
                }
                butterfly_acc(s8, r, slab + j * DV);
            }
        } else {
            // ---- pass A: hat2 resident (40 h2 regs), logits fused into the
            // hat loop (2-int4 W transient, pairwise h2 packing). ----
            h2 hat2[NC][4];
            float cj[NC];
            float Z = 0.f;
#pragma unroll
            for (int j = 0; j < NC; ++j) {
                const int4* wp = wpg + j * 512;
#pragma unroll
                for (int kp = 0; kp < 4; ++kp) {
                    WChunk w0, w1;
                    w0.v = wp[(2 * kp) * 64];
                    w1.v = wp[(2 * kp + 1) * 64];
                    float a0 = 0.f, a1 = 0.f;
#pragma unroll
                    for (int q = 0; q < 4; ++q) {
                        a0 = fdot2(xu.p[q], w0.p[q], a0);
                        a1 = fdot2(xu.p[q], w1.p[q], a1);
                    }
                    hat2[j][kp] = h2{(_Float16)a0, (_Float16)a1};
                }
                XFrag vv;
                vv.v = *(const int4*)(v2s + (j * 8 + h * 4));
                float ah = 0.f;
#pragma unroll
                for (int q = 0; q < 4; ++q) ah = fdot2(hat2[j][q], vv.p[q], ah);
                const float lt = bias[i * NC + j] + ah + __shfl_xor(ah, 32);
                const float e = __expf(lt);
                cj[j] = e;
                Z += e;
            }
            const float rz = 1.f / Z;

            // ---- pass B: weighted sum from resident hat2 (1/Z folded in) ----
#pragma unroll
            for (int j = 0; j < NC; ++j) {
                const float cn = cj[j] * rz;
                float s8[8];
#pragma unroll
                for (int q = 0; q < 4; ++q) {
                    s8[2 * q]     = cn * (float)hat2[j][q].x;
                    s8[2 * q + 1] = cn * (float)hat2[j][q].y;
                }
                butterfly_acc(s8, r, slab + j * DV);
            }
        }
    }
    __syncthreads();

    // ---- reduce slabs + squash (+ v1 add for vsum) ----
    if (tid < SOUT) {
        float sv = 0.f;
#pragma unroll
        for (int ww = 0; ww < NWAVE; ++ww) sv += s_part[ww * SOUT + tid];
        float s2 = sv * sv;
#pragma unroll
        for (int mk = 8; mk >= 1; mk >>= 1) s2 += __shfl_xor(s2, mk, 16);
        const float scale = sqrtf(s2) / (1.f + s2);
        float vv = scale * sv;
        if constexpr (RD == 1) vv += vkeep;  // vsum = v1 + v2
        v_out[(size_t)b * SOUT + tid] = vv;
    }
}

extern "C" void kernel_launch(void* const* d_in, const int* in_sizes, int n_in,
                              void* d_out, int out_size, void* d_ws, size_t ws_size,
                              hipStream_t stream) {
    const float* X = (const float*)d_in[0];     // [256,1152,8]
    const float* W = (const float*)d_in[1];     // [1152,10,8,16]
    const float* bias = (const float*)d_in[2];  // [1,1152,10]
    float* out = (float*)d_out;

    // ws layout: Wc (2.95MB) | v1 (160KB) | vsum (160KB)
    int4* Wc = (int4*)d_ws;
    float* v1 = (float*)(Wc + NW / 8);
    float* vsum = v1 + (size_t)NB * SOUT;

    wprep_kernel<<<dim3(720), dim3(256), 0, stream>>>(W, Wc);

    dim3 grid(NB);
    round_caps<0><<<grid, TPB, 0, stream>>>(X, Wc, bias, nullptr, v1);
    round_caps<1><<<grid, TPB, 0, stream>>>(X, Wc, bias, v1, vsum);
    round_caps<2><<<grid, TPB, 0, stream>>>(X, Wc, bias, vsum, out);
}